// Round 1
// baseline (1938.578 us; speedup 1.0000x reference)
//
#include <hip/hip_runtime.h>
#include <math.h>

// DigitCaps dynamic routing, fully fused (u_hat never materialized in HBM).
// B=512, I=1152 in_caps, K=8 in_dim, C=10 classes, D=16 caps_dim, 3 routing iters.
//
// Mapping (pass kernels): block=256 threads; lane = b within tile of 32 (t&31),
// stripe = t>>5 in [0,8) picks i. Each block: 32 b x 16 i. Grid (72, 16).
// W loads are half-wave-uniform (same address across 32 lanes -> broadcast).
// u_hat[c][d] (160 f32) lives in registers (fully unrolled c,d loops).
// s accumulated in LDS tile [cd][b] with pitch 33 (conflict-free ds_add_f32),
// then flushed as per-block partials (no global atomics) and reduced+squashed
// in a follow-up kernel. Fallback path uses global atomics if ws is small.

#define CD 160
#define LDS_PITCH 33
#define NB_B 32
#define NSTRIPE 8
#define ITERS 2
#define ICHUNK (NSTRIPE * ITERS)   // 16 i per block
#define NCH (1152 / ICHUNK)        // 72 i-chunks

__device__ __forceinline__ float fp_atomic_add_lds(float* p, float v) {
#if defined(__HIP_DEVICE_COMPILE__)
    return unsafeAtomicAdd(p, v);   // ds_add_f32 on gfx90a+/gfx950
#else
    return 0.f;
#endif
}

template <int PASS>
__global__ __launch_bounds__(256, 2)
void pass_kernel(const float* __restrict__ u, const float* __restrict__ W,
                 const float* __restrict__ v0g, const float* __restrict__ v1g,
                 float* __restrict__ part, float* __restrict__ s_atomic)
{
    __shared__ float s_tile[CD * LDS_PITCH];
    __shared__ float v0_t[CD * LDS_PITCH];
    __shared__ float v1_t[CD * LDS_PITCH];

    const int t      = threadIdx.x;
    const int bl     = t & 31;
    const int stripe = t >> 5;
    const int b0     = blockIdx.y * NB_B;
    const int b      = b0 + bl;
    const int ibase  = blockIdx.x * ICHUNK;

    for (int idx = t; idx < CD * LDS_PITCH; idx += 256) s_tile[idx] = 0.0f;
    if (PASS >= 1) {
        for (int idx = t; idx < NB_B * CD; idx += 256) {
            int b_l = idx / CD, cd = idx - b_l * CD;
            v0_t[cd * LDS_PITCH + b_l] = v0g[(size_t)(b0 + b_l) * CD + cd];
            if (PASS >= 2)
                v1_t[cd * LDS_PITCH + b_l] = v1g[(size_t)(b0 + b_l) * CD + cd];
        }
    }
    __syncthreads();

    const float* ub = u + (size_t)b * (1152 * 8);

    for (int iter = 0; iter < ITERS; ++iter) {
        const int i = ibase + stripe + NSTRIPE * iter;

        const float4* up = (const float4*)(ub + i * 8);
        const float4 ua = up[0];
        const float4 uc = up[1];
        const float* Wp = W + (size_t)i * (10 * 16 * 8);

        float uh[CD];
        float logit[10];

        #pragma unroll
        for (int c = 0; c < 10; ++c) {
            float a0 = 0.0f, a1 = 0.0f;
            #pragma unroll
            for (int d = 0; d < 16; ++d) {
                const float4* wp = (const float4*)(Wp + (c * 16 + d) * 8);
                const float4 w0 = wp[0];
                const float4 w1 = wp[1];
                float h = w0.x * ua.x + w0.y * ua.y + w0.z * ua.z + w0.w * ua.w
                        + w1.x * uc.x + w1.y * uc.y + w1.z * uc.z + w1.w * uc.w;
                uh[c * 16 + d] = h;
                if (PASS >= 1) a0 += h * v0_t[(c * 16 + d) * LDS_PITCH + bl];
                if (PASS >= 2) a1 += h * v1_t[(c * 16 + d) * LDS_PITCH + bl];
            }
            logit[c] = a0 + a1;   // pass1: b1 = agr0 ; pass2: b2 = agr0 + agr1
        }

        float coef[10];
        if (PASS == 0) {
            #pragma unroll
            for (int c = 0; c < 10; ++c) coef[c] = 0.1f;   // softmax of zeros
        } else {
            float m = logit[0];
            #pragma unroll
            for (int c = 1; c < 10; ++c) m = fmaxf(m, logit[c]);
            float ssum = 0.0f;
            #pragma unroll
            for (int c = 0; c < 10; ++c) {
                float e = __expf(logit[c] - m);
                coef[c] = e;
                ssum += e;
            }
            float r = 1.0f / ssum;
            #pragma unroll
            for (int c = 0; c < 10; ++c) coef[c] *= r;
        }

        #pragma unroll
        for (int c = 0; c < 10; ++c) {
            #pragma unroll
            for (int d = 0; d < 16; ++d) {
                fp_atomic_add_lds(&s_tile[(c * 16 + d) * LDS_PITCH + bl],
                                  coef[c] * uh[c * 16 + d]);
            }
        }
    }
    __syncthreads();

    if (part) {
        // Non-atomic per-block partial: part[(chunk*512 + b)*160 + cd]
        float* pout = part + ((size_t)blockIdx.x * 512 + b0) * CD;
        for (int idx = t; idx < NB_B * CD; idx += 256) {
            int b_l = idx / CD, cd = idx - b_l * CD;
            pout[idx] = s_tile[cd * LDS_PITCH + b_l];
        }
    } else {
        for (int idx = t; idx < NB_B * CD; idx += 256) {
            int b_l = idx / CD, cd = idx - b_l * CD;
#if defined(__HIP_DEVICE_COMPILE__)
            unsafeAtomicAdd(&s_atomic[(size_t)(b0 + b_l) * CD + cd],
                            s_tile[cd * LDS_PITCH + b_l]);
#endif
        }
    }
}

// Reduce 72 partials and apply squash. 8 b-rows per block, grid 64.
__global__ void reduce_squash(const float* __restrict__ part, float* __restrict__ vout)
{
    __shared__ float acc_s[8 * CD];
    const int t  = threadIdx.x;
    const int b0 = blockIdx.x * 8;

    float acc[5] = {0.f, 0.f, 0.f, 0.f, 0.f};
    for (int ch = 0; ch < NCH; ++ch) {
        const float* p = part + ((size_t)ch * 512 + b0) * CD;
        #pragma unroll
        for (int j = 0; j < 5; ++j) acc[j] += p[t + 256 * j];
    }
    #pragma unroll
    for (int j = 0; j < 5; ++j) acc_s[t + 256 * j] = acc[j];
    __syncthreads();

    if (t < 80) {   // 8 b x 10 c rows
        float sv[16];
        float ns = 0.0f;
        #pragma unroll
        for (int d = 0; d < 16; ++d) {
            float x = acc_s[t * 16 + d];
            sv[d] = x;
            ns += x * x;
        }
        float scale = ns / ((1.0f + ns) * (sqrtf(ns) + 1e-8f));
        float* o = vout + ((size_t)b0 * 10 + t) * 16;
        #pragma unroll
        for (int d = 0; d < 16; ++d) o[d] = sv[d] * scale;
    }
}

// Fallback squash (atomic path): one thread per (b,c) row.
__global__ void squash_only(const float* __restrict__ s, float* __restrict__ vout)
{
    int r = blockIdx.x * 256 + threadIdx.x;
    if (r >= 512 * 10) return;
    const float* sp = s + (size_t)r * 16;
    float sv[16];
    float ns = 0.0f;
    #pragma unroll
    for (int d = 0; d < 16; ++d) {
        float x = sp[d];
        sv[d] = x;
        ns += x * x;
    }
    float scale = ns / ((1.0f + ns) * (sqrtf(ns) + 1e-8f));
    float* o = vout + (size_t)r * 16;
    #pragma unroll
    for (int d = 0; d < 16; ++d) o[d] = sv[d] * scale;
}

extern "C" void kernel_launch(void* const* d_in, const int* in_sizes, int n_in,
                              void* d_out, int out_size, void* d_ws, size_t ws_size,
                              hipStream_t stream)
{
    const float* u = (const float*)d_in[0];   // [512,1152,8]
    const float* W = (const float*)d_in[1];   // [1152,10,16,8]
    float* out = (float*)d_out;               // [512,10,16]

    float* v0 = (float*)d_ws;                 // 81920 f32
    float* v1 = v0 + 81920;                   // 81920 f32

    const size_t needA = ((size_t)2 * 81920 + (size_t)NCH * 512 * CD) * sizeof(float); // ~24.3 MB

    dim3 grid(NCH, 16);
    dim3 blk(256);

    if (ws_size >= needA) {
        float* part = v1 + 81920;             // [72][512][160] f32
        pass_kernel<0><<<grid, blk, 0, stream>>>(u, W, nullptr, nullptr, part, nullptr);
        reduce_squash<<<64, 256, 0, stream>>>(part, v0);
        pass_kernel<1><<<grid, blk, 0, stream>>>(u, W, v0, nullptr, part, nullptr);
        reduce_squash<<<64, 256, 0, stream>>>(part, v1);
        pass_kernel<2><<<grid, blk, 0, stream>>>(u, W, v0, v1, part, nullptr);
        reduce_squash<<<64, 256, 0, stream>>>(part, out);
    } else {
        // Low-workspace fallback: single s buffer + global fp32 atomics.
        float* s = v1 + 81920;                // 81920 f32
        hipMemsetAsync(s, 0, 81920 * sizeof(float), stream);
        pass_kernel<0><<<grid, blk, 0, stream>>>(u, W, nullptr, nullptr, nullptr, s);
        squash_only<<<20, 256, 0, stream>>>(s, v0);
        hipMemsetAsync(s, 0, 81920 * sizeof(float), stream);
        pass_kernel<1><<<grid, blk, 0, stream>>>(u, W, v0, nullptr, nullptr, s);
        squash_only<<<20, 256, 0, stream>>>(s, v1);
        hipMemsetAsync(s, 0, 81920 * sizeof(float), stream);
        pass_kernel<2><<<grid, blk, 0, stream>>>(u, W, v0, v1, nullptr, s);
        squash_only<<<20, 256, 0, stream>>>(s, out);
    }
}